// Round 1
// baseline (262.838 us; speedup 1.0000x reference)
//
#include <hip/hip_runtime.h>
#include <hip/hip_bf16.h>
#include <hip/hip_fp16.h>
#include <stdint.h>

#define M_DIM 4096   // B*S = 2*2048
#define N_DIM 4096   // O
#define K_DIM 4096   // I
#define GROUPSZ 128
#define MAXQ 15.0f

#define BM 128
#define BN 128
#define BK 32

typedef __attribute__((ext_vector_type(8))) short short8;
typedef __attribute__((ext_vector_type(4))) float f32x4;

// ---------------- quant: groupwise asymmetric fake-quant, f32 -> bf16 ----------------
// one wave per group of 128; lane holds 2 elements
__global__ __launch_bounds__(256) void quant_kernel(
    const float* __restrict__ weight, const float* __restrict__ value,
    const float* __restrict__ min_scale, const float* __restrict__ max_scale,
    __hip_bfloat16* __restrict__ wq)
{
    const int tid  = threadIdx.x;
    const int wave = tid >> 6;
    const int lane = tid & 63;
    const long g    = (long)blockIdx.x * 4 + wave;
    const long base = g * GROUPSZ + lane * 2;

    const float2 w = *(const float2*)(weight + base);
    const float2 v = *(const float2*)(value  + base);

    float mn = fminf(w.x, w.y);
    float mx = fmaxf(w.x, w.y);
#pragma unroll
    for (int off = 32; off >= 1; off >>= 1) {
        mn = fminf(mn, __shfl_xor(mn, off, 64));
        mx = fmaxf(mx, __shfl_xor(mx, off, 64));
    }
    mn = fminf(mn, 0.0f);                 // wmin_t
    mx = fmaxf(mx, 0.0f);                 // wmax_t

    const float ms = fminf(fmaxf(min_scale[g], -1.0f), 0.0f) + 1.0f;
    const float xs = fminf(fmaxf(max_scale[g], -1.0f), 0.0f) + 1.0f;
    float wmin = mn * ms;
    float wmax = mx * xs;
    if (wmin == 0.0f && wmax == 0.0f) { wmin = -1.0f; wmax = 1.0f; }

    // scale stored at fp16 precision then used as f32 (RTNE both ways)
    const float scale = (float)(_Float16)((wmax - wmin) / MAXQ);
    const float zp    = rintf(-wmin / scale);

    const float q0 = fminf(fmaxf(rintf(w.x / scale + v.x) + zp, 0.0f), MAXQ);
    const float q1 = fminf(fmaxf(rintf(w.y / scale + v.y) + zp, 0.0f), MAXQ);
    const float o0 = scale * (q0 - zp);
    const float o1 = scale * (q1 - zp);

    __hip_bfloat162 o;
    o.x = __float2bfloat16(o0);
    o.y = __float2bfloat16(o1);
    *(__hip_bfloat162*)(wq + base) = o;
}

// ---------------- x cast: f32 -> bf16, 8 elems/thread ----------------
__global__ __launch_bounds__(256) void cast_kernel(
    const float* __restrict__ x, __hip_bfloat16* __restrict__ xb)
{
    const long i = ((long)blockIdx.x * 256 + threadIdx.x) * 8;
    const float4 a = *(const float4*)(x + i);
    const float4 b = *(const float4*)(x + i + 4);
    union { short8 s; __hip_bfloat16 h[8]; } u;
    u.h[0] = __float2bfloat16(a.x);
    u.h[1] = __float2bfloat16(a.y);
    u.h[2] = __float2bfloat16(a.z);
    u.h[3] = __float2bfloat16(a.w);
    u.h[4] = __float2bfloat16(b.x);
    u.h[5] = __float2bfloat16(b.y);
    u.h[6] = __float2bfloat16(b.z);
    u.h[7] = __float2bfloat16(b.w);
    *(short8*)(xb + i) = u.s;
}

// ---------------- GEMM: C[m][n] = sum_k A[m][k]*B[n][k] + bias[n] ----------------
// m97 structure: 128x128 tile, 4 waves (2x2), 4x4 16x16x32 frags/wave,
// global_load_lds width=16 staging, double-buffered LDS, 2-phase pipeline.
__global__ __launch_bounds__(256) void gemm_kernel(
    const __hip_bfloat16* __restrict__ A,   // [M][K] bf16 (x)
    const __hip_bfloat16* __restrict__ B,   // [N][K] bf16 (wq)
    const float* __restrict__ bias,
    float* __restrict__ C)                  // [M][N] f32
{
    __shared__ __align__(16) __hip_bfloat16 As[2][BM * BK];
    __shared__ __align__(16) __hip_bfloat16 Bs[2][BM * BK];

    const int tid  = threadIdx.x;
    const int lane = tid & 63;
    const int wv   = tid >> 6;

    // XCD-aware swizzle (nwg = 1024, divisible by 8 -> bijective)
    const int bid = blockIdx.x;
    const int cpx = gridDim.x >> 3;
    const int swz = (bid & 7) * cpx + (bid >> 3);
    const int tm = swz >> 5;          // 32 N-tiles
    const int tn = swz & 31;
    const int brow = tm * BM;
    const int bcol = tn * BN;
    const int wm = wv >> 1;           // 2x2 wave grid
    const int wn = wv & 1;

    // staging geometry: chunk c covers LDS bytes [c*1024, c*1024+1024)
    //   lane l -> row = c*16 + l/4, col = (l%4)*8 bf16 (16B)
    const int st_r = lane >> 2;
    const int st_c = (lane & 3) * 8;

    f32x4 acc[4][4] = {};

#define STAGE(buf, kt)                                                              \
    {                                                                               \
        const int k0 = (kt) * BK;                                                   \
        _Pragma("unroll")                                                           \
        for (int i = 0; i < 2; ++i) {                                               \
            const int c   = wv * 2 + i;                                             \
            const int row = c * 16 + st_r;                                          \
            const __hip_bfloat16* ga = A + (size_t)(brow + row) * K_DIM + k0 + st_c;\
            const __hip_bfloat16* gb = B + (size_t)(bcol + row) * K_DIM + k0 + st_c;\
            __builtin_amdgcn_global_load_lds(                                       \
                (const __attribute__((address_space(1))) void*)ga,                  \
                (__attribute__((address_space(3))) void*)(&As[buf][c * 512]),       \
                16, 0, 0);                                                          \
            __builtin_amdgcn_global_load_lds(                                       \
                (const __attribute__((address_space(1))) void*)gb,                  \
                (__attribute__((address_space(3))) void*)(&Bs[buf][c * 512]),       \
                16, 0, 0);                                                          \
        }                                                                           \
    }

    STAGE(0, 0);
    __syncthreads();   // drains vmcnt(0): tile 0 resident

    const int NT = K_DIM / BK;   // 128
    int cur = 0;
    const int ro = lane & 15;
    const int ko = (lane >> 4) * 8;

    for (int kt = 0; kt < NT; ++kt) {
        if (kt + 1 < NT) STAGE(cur ^ 1, kt + 1);

        short8 a[4], b[4];
#pragma unroll
        for (int mi = 0; mi < 4; ++mi)
            a[mi] = *(const short8*)&As[cur][(wm * 64 + mi * 16 + ro) * BK + ko];
#pragma unroll
        for (int nj = 0; nj < 4; ++nj)
            b[nj] = *(const short8*)&Bs[cur][(wn * 64 + nj * 16 + ro) * BK + ko];

        __builtin_amdgcn_s_setprio(1);
#pragma unroll
        for (int mi = 0; mi < 4; ++mi)
#pragma unroll
            for (int nj = 0; nj < 4; ++nj)
                acc[mi][nj] = __builtin_amdgcn_mfma_f32_16x16x32_bf16(
                    a[mi], b[nj], acc[mi][nj], 0, 0, 0);
        __builtin_amdgcn_s_setprio(0);

        __syncthreads();   // next tile staged; cur buffer free for reuse
        cur ^= 1;
    }

    // epilogue: C/D frag layout col = lane&15, row = (lane>>4)*4 + reg
    const int col   = lane & 15;
    const int rbase = (lane >> 4) * 4;
    float bv[4];
#pragma unroll
    for (int nj = 0; nj < 4; ++nj)
        bv[nj] = bias[bcol + wn * 64 + nj * 16 + col];

#pragma unroll
    for (int mi = 0; mi < 4; ++mi) {
        const int mrow = brow + wm * 64 + mi * 16 + rbase;
#pragma unroll
        for (int r = 0; r < 4; ++r) {
            float* crow = C + (size_t)(mrow + r) * N_DIM + bcol + wn * 64 + col;
#pragma unroll
            for (int nj = 0; nj < 4; ++nj)
                crow[nj * 16] = acc[mi][nj][r] + bv[nj];
        }
    }
#undef STAGE
}

extern "C" void kernel_launch(void* const* d_in, const int* in_sizes, int n_in,
                              void* d_out, int out_size, void* d_ws, size_t ws_size,
                              hipStream_t stream) {
    const float* x         = (const float*)d_in[0];
    const float* weight    = (const float*)d_in[1];
    const float* bias      = (const float*)d_in[2];
    const float* value     = (const float*)d_in[3];
    const float* min_scale = (const float*)d_in[4];
    const float* max_scale = (const float*)d_in[5];
    float* out = (float*)d_out;

    __hip_bfloat16* xb  = (__hip_bfloat16*)d_ws;                       // [M][K] bf16
    __hip_bfloat16* wqb = xb + (size_t)M_DIM * K_DIM;                  // [N][K] bf16

    // quant: 131072 groups, 4 groups/block
    quant_kernel<<<(N_DIM * K_DIM / GROUPSZ) / 4, 256, 0, stream>>>(
        weight, value, min_scale, max_scale, wqb);
    // cast x: 8 elems/thread
    cast_kernel<<<(M_DIM * K_DIM) / (256 * 8), 256, 0, stream>>>(x, xb);
    // GEMM 4096^3
    gemm_kernel<<<(M_DIM / BM) * (N_DIM / BN), 256, 0, stream>>>(xb, wqb, bias, out);
}

// Round 2
// 172.148 us; speedup vs baseline: 1.5268x; 1.5268x over previous
//
#include <hip/hip_runtime.h>
#include <hip/hip_bf16.h>
#include <hip/hip_fp16.h>
#include <stdint.h>

#define M_DIM 4096   // B*S = 2*2048
#define N_DIM 4096   // O
#define K_DIM 4096   // I
#define GROUPSZ 128
#define MAXQ 15.0f

// 256x256 8-phase template geometry
#define BM 256
#define BN 256
#define BK 64
#define T_TILES (K_DIM / BK)   // 64

typedef __attribute__((ext_vector_type(8))) short short8;
typedef __attribute__((ext_vector_type(4))) float f32x4;

// ---------------- quant: groupwise asymmetric fake-quant, f32 -> bf16 ----------------
__global__ __launch_bounds__(256) void quant_kernel(
    const float* __restrict__ weight, const float* __restrict__ value,
    const float* __restrict__ min_scale, const float* __restrict__ max_scale,
    __hip_bfloat16* __restrict__ wq)
{
    const int tid  = threadIdx.x;
    const int wave = tid >> 6;
    const int lane = tid & 63;
    const long g    = (long)blockIdx.x * 4 + wave;
    const long base = g * GROUPSZ + lane * 2;

    const float2 w = *(const float2*)(weight + base);
    const float2 v = *(const float2*)(value  + base);

    float mn = fminf(w.x, w.y);
    float mx = fmaxf(w.x, w.y);
#pragma unroll
    for (int off = 32; off >= 1; off >>= 1) {
        mn = fminf(mn, __shfl_xor(mn, off, 64));
        mx = fmaxf(mx, __shfl_xor(mx, off, 64));
    }
    mn = fminf(mn, 0.0f);
    mx = fmaxf(mx, 0.0f);

    const float ms = fminf(fmaxf(min_scale[g], -1.0f), 0.0f) + 1.0f;
    const float xs = fminf(fmaxf(max_scale[g], -1.0f), 0.0f) + 1.0f;
    float wmin = mn * ms;
    float wmax = mx * xs;
    if (wmin == 0.0f && wmax == 0.0f) { wmin = -1.0f; wmax = 1.0f; }

    const float scale = (float)(_Float16)((wmax - wmin) / MAXQ);
    const float zp    = rintf(-wmin / scale);

    const float q0 = fminf(fmaxf(rintf(w.x / scale + v.x) + zp, 0.0f), MAXQ);
    const float q1 = fminf(fmaxf(rintf(w.y / scale + v.y) + zp, 0.0f), MAXQ);
    const float o0 = scale * (q0 - zp);
    const float o1 = scale * (q1 - zp);

    __hip_bfloat162 o;
    o.x = __float2bfloat16(o0);
    o.y = __float2bfloat16(o1);
    *(__hip_bfloat162*)(wq + base) = o;
}

// ---------------- x cast: f32 -> bf16, 8 elems/thread ----------------
__global__ __launch_bounds__(256) void cast_kernel(
    const float* __restrict__ x, __hip_bfloat16* __restrict__ xb)
{
    const long i = ((long)blockIdx.x * 256 + threadIdx.x) * 8;
    const float4 a = *(const float4*)(x + i);
    const float4 b = *(const float4*)(x + i + 4);
    union { short8 s; __hip_bfloat16 h[8]; } u;
    u.h[0] = __float2bfloat16(a.x);
    u.h[1] = __float2bfloat16(a.y);
    u.h[2] = __float2bfloat16(a.z);
    u.h[3] = __float2bfloat16(a.w);
    u.h[4] = __float2bfloat16(b.x);
    u.h[5] = __float2bfloat16(b.y);
    u.h[6] = __float2bfloat16(b.z);
    u.h[7] = __float2bfloat16(b.w);
    *(short8*)(xb + i) = u.s;
}

// ---------------- GEMM: 256x256 tile, BK=64, 8 waves, 8-phase pipeline ----------------
// C[m][n] = sum_k A[m][k]*B[n][k] + bias[n]
// LDS 128 KiB: A dbuf [2][256][64] + B dbuf [2][256][64] bf16, XOR-swizzled
// (linear global_load_lds dest + inverse-swizzled global source + swizzled ds_read).
__global__ __launch_bounds__(512, 2) void gemm_kernel(
    const __hip_bfloat16* __restrict__ A,   // [M][K] bf16 (x)
    const __hip_bfloat16* __restrict__ B,   // [N][K] bf16 (wq)
    const float* __restrict__ bias,
    float* __restrict__ C)                  // [M][N] f32
{
    __shared__ __align__(16) char lds[131072];
    // A buf c: bytes [c*32768, +32768);  B buf c: [65536 + c*32768, +32768)
    // tile layout: row r (0..255) at r*128 bytes; 16B slot s holds logical
    // slot s ^ (r&7)  (XOR involution, applied on both write-source and read).

    const int tid  = threadIdx.x;
    const int lane = tid & 63;
    const int wv   = tid >> 6;
    const int wm   = wv >> 2;          // 2 (M) x 4 (N) wave grid
    const int wn   = wv & 3;

    // XCD-aware bijective swizzle (256 blocks % 8 == 0)
    const int bid = blockIdx.x;
    const int swz = (bid & 7) * (gridDim.x >> 3) + (bid >> 3);
    const int brow = (swz >> 4) * BM;  // 16x16 tile grid
    const int bcol = (swz & 15) * BN;

    // staging: thread covers rows (h*128 + inst*64 + (tid>>3)), 16B at logical
    // slot (tid&7)^((tid>>3)&7); LDS dest linear (wave-uniform base + lane*16)
    const int stg_r = tid >> 3;                                  // 0..63
    const int cc    = ((tid & 7) ^ (stg_r & 7)) * 8;             // elems

#define STAGE(XP, rowbase, h, tau, ldsbase)                                         \
    { _Pragma("unroll")                                                             \
      for (int inst = 0; inst < 2; ++inst) {                                        \
        const __hip_bfloat16* g = (XP) +                                            \
            (size_t)((rowbase) + (h) * 128 + inst * 64 + stg_r) * K_DIM +           \
            (tau) * 64 + cc;                                                        \
        __builtin_amdgcn_global_load_lds(                                           \
            (const __attribute__((address_space(1))) void*)g,                       \
            (__attribute__((address_space(3))) void*)(lds + (ldsbase) +             \
                (h) * 16384 + inst * 8192 + (wv << 10)),                            \
            16, 0, 0);                                                              \
      } }

    // ds_read geometry: frag (row-block, kk): lane holds row ro of block,
    // k = kk*32 + hi*8 .. +7; physical slot = (kk*4+hi) ^ (ro&7)
    const int ro = lane & 15;
    const int hi = lane >> 4;
    const int slot0 = ((0 + hi) ^ (ro & 7)) << 4;
    const int slot1 = ((4 + hi) ^ (ro & 7)) << 4;
    const int rbA = (wm * 128 + ro) * 128;
    const int rbB = (wn * 64  + ro) * 128;

    f32x4 acc[8][4] = {};

    // prologue: tile0 {B0,B1,A0,A1} + tile1 {B0,B1,A0}; keep 3 units in flight
    STAGE(B, bcol, 0, 0, 65536);
    STAGE(B, bcol, 1, 0, 65536);
    STAGE(A, brow, 0, 0, 0);
    STAGE(A, brow, 1, 0, 0);
    STAGE(B, bcol, 0, 1, 65536 + 32768);
    STAGE(B, bcol, 1, 1, 65536 + 32768);
    STAGE(A, brow, 0, 1, 32768);
    asm volatile("s_waitcnt vmcnt(6)" ::: "memory");   // tile 0 fully resident
    __builtin_amdgcn_s_barrier();

#define MFMA_PAIR(M0)                                                               \
    { _Pragma("unroll")                                                             \
      for (int n = 0; n < 4; ++n) {                                                 \
        acc[M0][n]     = __builtin_amdgcn_mfma_f32_16x16x32_bf16(af[M0][0],   b0[n][0], acc[M0][n],     0, 0, 0); \
        acc[M0 + 1][n] = __builtin_amdgcn_mfma_f32_16x16x32_bf16(af[M0+1][0], b0[n][0], acc[M0 + 1][n], 0, 0, 0); \
        acc[M0][n]     = __builtin_amdgcn_mfma_f32_16x16x32_bf16(af[M0][1],   b0[n][1], acc[M0][n],     0, 0, 0); \
        acc[M0 + 1][n] = __builtin_amdgcn_mfma_f32_16x16x32_bf16(af[M0+1][1], b0[n][1], acc[M0 + 1][n], 0, 0, 0); \
      } }

    for (int t = 0; t < T_TILES; ++t) {
        const int c = t & 1;
        const char* bA = lds + c * 32768 + rbA;
        const char* bB = lds + 65536 + c * 32768 + rbB;

        short8 b0[4][2];
        short8 af[8][2];

        // ---- phase 1: read all B + A m0-3; stage A-half1(t+1); MFMA m0,m1 ----
#pragma unroll
        for (int n = 0; n < 4; ++n) {
            b0[n][0] = *(const short8*)(bB + n * 2048 + slot0);
            b0[n][1] = *(const short8*)(bB + n * 2048 + slot1);
        }
#pragma unroll
        for (int m = 0; m < 4; ++m) {
            af[m][0] = *(const short8*)(bA + m * 2048 + slot0);
            af[m][1] = *(const short8*)(bA + m * 2048 + slot1);
        }
        if (t + 1 < T_TILES) { STAGE(A, brow, 1, t + 1, (c ^ 1) * 32768); }
        __builtin_amdgcn_s_barrier();
        asm volatile("s_waitcnt lgkmcnt(0)" ::: "memory");
        __builtin_amdgcn_s_setprio(1);
        MFMA_PAIR(0);
        __builtin_amdgcn_s_setprio(0);
        __builtin_amdgcn_s_barrier();

        // ---- phase 2: read A m4,m5; stage B-half0(t+2); MFMA m2,m3 ----
#pragma unroll
        for (int m = 4; m < 6; ++m) {
            af[m][0] = *(const short8*)(bA + m * 2048 + slot0);
            af[m][1] = *(const short8*)(bA + m * 2048 + slot1);
        }
        if (t + 2 < T_TILES) { STAGE(B, bcol, 0, t + 2, 65536 + c * 32768); }
        __builtin_amdgcn_s_barrier();
        asm volatile("s_waitcnt lgkmcnt(0)" ::: "memory");
        __builtin_amdgcn_s_setprio(1);
        MFMA_PAIR(2);
        __builtin_amdgcn_s_setprio(0);
        __builtin_amdgcn_s_barrier();

        // ---- phase 3: read A m6,m7; stage B-half1(t+2); MFMA m4,m5 ----
#pragma unroll
        for (int m = 6; m < 8; ++m) {
            af[m][0] = *(const short8*)(bA + m * 2048 + slot0);
            af[m][1] = *(const short8*)(bA + m * 2048 + slot1);
        }
        if (t + 2 < T_TILES) { STAGE(B, bcol, 1, t + 2, 65536 + c * 32768); }
        __builtin_amdgcn_s_barrier();
        asm volatile("s_waitcnt lgkmcnt(0)" ::: "memory");
        __builtin_amdgcn_s_setprio(1);
        MFMA_PAIR(4);
        __builtin_amdgcn_s_setprio(0);
        __builtin_amdgcn_s_barrier();

        // ---- phase 4: stage A-half0(t+2); counted vmcnt; MFMA m6,m7 ----
        if (t + 2 < T_TILES) { STAGE(A, brow, 0, t + 2, c * 32768); }
        if (t < T_TILES - 2) { asm volatile("s_waitcnt vmcnt(6)" ::: "memory"); }
        else                 { asm volatile("s_waitcnt vmcnt(0)" ::: "memory"); }
        __builtin_amdgcn_s_barrier();
        __builtin_amdgcn_s_setprio(1);
        MFMA_PAIR(6);
        __builtin_amdgcn_s_setprio(0);
        __builtin_amdgcn_s_barrier();
    }

    // epilogue: C/D frag layout col = lane&15, row = hi*4 + reg
    const int col   = lane & 15;
    const int rbase = hi * 4;
    float bv[4];
#pragma unroll
    for (int n = 0; n < 4; ++n)
        bv[n] = bias[bcol + wn * 64 + n * 16 + col];

#pragma unroll
    for (int m = 0; m < 8; ++m) {
        const int mrow = brow + wm * 128 + m * 16 + rbase;
#pragma unroll
        for (int r = 0; r < 4; ++r) {
            float* crow = C + (size_t)(mrow + r) * N_DIM + bcol + wn * 64 + col;
#pragma unroll
            for (int n = 0; n < 4; ++n)
                crow[n * 16] = acc[m][n][r] + bv[n];
        }
    }
#undef STAGE
#undef MFMA_PAIR
}

extern "C" void kernel_launch(void* const* d_in, const int* in_sizes, int n_in,
                              void* d_out, int out_size, void* d_ws, size_t ws_size,
                              hipStream_t stream) {
    const float* x         = (const float*)d_in[0];
    const float* weight    = (const float*)d_in[1];
    const float* bias      = (const float*)d_in[2];
    const float* value     = (const float*)d_in[3];
    const float* min_scale = (const float*)d_in[4];
    const float* max_scale = (const float*)d_in[5];
    float* out = (float*)d_out;

    __hip_bfloat16* xb  = (__hip_bfloat16*)d_ws;                       // [M][K] bf16
    __hip_bfloat16* wqb = xb + (size_t)M_DIM * K_DIM;                  // [N][K] bf16

    quant_kernel<<<(N_DIM * K_DIM / GROUPSZ) / 4, 256, 0, stream>>>(
        weight, value, min_scale, max_scale, wqb);
    cast_kernel<<<(M_DIM * K_DIM) / (256 * 8), 256, 0, stream>>>(x, xb);
    gemm_kernel<<<(M_DIM / BM) * (N_DIM / BN), 512, 0, stream>>>(xb, wqb, bias, out);
}